// Round 11
// baseline (484.481 us; speedup 1.0000x reference)
//
#include <hip/hip_runtime.h>
#include <stdint.h>

// UnarySqrt scan, T=64 steps, N=2^20 channels, exact {0,1} floats.
//   per step: p = x*(1-tr); out = tr + p; tr' = p
//
// R1..R7: compiler collapses register pipelines (VGPR counts prove it) ->
// effective MLP ~1 -> ~2.2 TB/s latency-bound. Harness fill kernel sustains
// 6.5 TB/s in the same loop -> memory system has 2x+ headroom.
//
// R8/R10 design: wave-private async global->LDS DMA staging
// (__builtin_amdgcn_global_load_lds, 16 B/lane, m97-verified), barrier-free.
// R10 FAILED with NaN: LLVM's waitcnt pass does NOT insert the vmcnt wait
// between an LDS-DMA and a dependent ds_read (m97 always had __syncthreads
// there). Fix: explicit wave-level s_waitcnt vmcnt(0) after each DMA batch,
// and lgkmcnt(0) before the next batch so pending ds_reads can't race the
// next chunk's DMA arrival into the same LDS slots.
//
// Layout (m104/m108 rule: wave-uniform base + lane*16, contiguous in lane
// order): lds[j*256 + tid] byte addr = j*4096 + wave*1024 + lane*16.  OK.

typedef float v4f __attribute__((ext_vector_type(4)));

#define AS1 __attribute__((address_space(1)))
#define AS3 __attribute__((address_space(3)))

#define CHUNK_ROWS 16
#define NCHUNKS 4  // 64 rows total

__global__ __launch_bounds__(256) void UnarySqrt_kernel(
    const float* __restrict__ in,      // [64, N]
    const float* __restrict__ trace0,  // [N]
    float* __restrict__ out,           // [64, N]
    int stride4)                        // N/4
{
    __shared__ v4f lds[CHUNK_ROWS * 256];  // 64 KB; per-row 1 KB wave slices

    const int tid = threadIdx.x;
    const size_t g = (size_t)blockIdx.x * 256 + tid;  // v4f channel group

    const v4f* in4  = (const v4f*)in;
    v4f*       out4 = (v4f*)out;

    v4f tr = ((const v4f*)trace0)[g];

    for (int c = 0; c < NCHUNKS; ++c) {
        // Defensive: make sure this wave's ds_reads of the previous chunk are
        // fully out of the LDS pipe before the DMA can overwrite those slots.
        if (c > 0) {
            asm volatile("s_waitcnt lgkmcnt(0)" ::: "memory");
        }

        // Issue 16 async DMA loads: rows c*16 .. c*16+15, this wave's slice.
        #pragma unroll
        for (int j = 0; j < CHUNK_ROWS; ++j) {
            const v4f* gp = &in4[(size_t)(c * CHUNK_ROWS + j) * (size_t)stride4 + g];
            v4f* lp = &lds[j * 256 + tid];
            __builtin_amdgcn_global_load_lds(
                (const AS1 void*)(const void*)gp,
                (AS3 void*)(void*)lp,
                16, 0, 0);
        }

        // REQUIRED: the compiler does NOT model DMA->ds_read dependencies.
        // Wave-level drain of this wave's outstanding VMEM (16 DMAs + any
        // not-yet-acked stores). No __syncthreads needed: wave-private slices.
        asm volatile("s_waitcnt vmcnt(0)" ::: "memory");

        #pragma unroll
        for (int j = 0; j < CHUNK_ROWS; ++j) {
            v4f x = lds[j * 256 + tid];
            v4f p = x * (1.0f - tr);
            v4f o = tr + p;
            out4[(size_t)(c * CHUNK_ROWS + j) * (size_t)stride4 + g] = o;
            tr = p;
        }
    }
}

// Generic fallback (correct for any T, N%4==0).
__global__ __launch_bounds__(256) void UnarySqrt_generic(
    const v4f* __restrict__ in, const v4f* __restrict__ trace0,
    v4f* __restrict__ out, int stride, int T)
{
    int idx = blockIdx.x * blockDim.x + threadIdx.x;
    if (idx >= stride) return;
    v4f tr = trace0[idx];
    for (int t = 0; t < T; ++t) {
        v4f x = in[(size_t)t * stride + idx];
        v4f p = x * (1.0f - tr);
        out[(size_t)t * stride + idx] = tr + p;
        tr = p;
    }
}

extern "C" void kernel_launch(void* const* d_in, const int* in_sizes, int n_in,
                              void* d_out, int out_size, void* d_ws, size_t ws_size,
                              hipStream_t stream) {
    const float* bits   = (const float*)d_in[0];  // [T, N]
    const float* trace0 = (const float*)d_in[1];  // [N]

    int N = in_sizes[1];
    int T = in_sizes[0] / N;
    int stride4 = N / 4;

    if (T == 64 && (N % 1024) == 0) {
        int grid = stride4 / 256;  // each block covers 256 v4f groups
        UnarySqrt_kernel<<<grid, 256, 0, stream>>>(bits, trace0, (float*)d_out, stride4);
    } else {
        int block = 256;
        int grid = (stride4 + block - 1) / block;
        UnarySqrt_generic<<<grid, block, 0, stream>>>(
            (const v4f*)bits, (const v4f*)trace0, (v4f*)d_out, stride4, T);
    }
}

// Round 12
// 446.588 us; speedup vs baseline: 1.0849x; 1.0849x over previous
//
#include <hip/hip_runtime.h>
#include <stdint.h>

// UnarySqrt scan, T=64 steps, N=2^20 channels, exact {0,1} floats.
//   per step: p = x*(1-tr); out = tr + p; tr' = p   (out = x|tr, tr' = x&~tr)
//
// Evidence so far: achieved read BW ~ (waves/CU) x (loads in flight per
// wave). R1/R3 (depth~1, 16-32 waves) -> 2.4 TB/s. R11 (depth 16, 8 waves,
// 50% duty from vmcnt(0) drains) -> 1.8 TB/s. R8 (depth~2, 32 waves) ->
// ~3.2 TB/s, best. Harness fill sustains 6.5 TB/s -> HW headroom exists.
//
// This version pushes the winning corner: 32 waves/CU AND a materialized
// per-thread load batch.
//   - 1024-thread blocks = 16 waves; 2 blocks/CU resident = 32 waves/CU.
//   - wave w owns a 4-row chunk (16 chunks x 4 rows = 64); lanes <-> 64 v4f
//     column groups per block.
//   - each thread: 4 independent dwordx4 loads + trace0 load, then an empty
//     asm tie on all 4 buffers AFTER the batch -> compiler must issue all 4
//     before phase 2 (only ~20 VGPRs tied; low pressure, no spill motive).
//   - chunk transfer function (F(0),F(1)) per channel; LDS exchange;
//     <=15 wave-uniform prefix folds; recompute + 4 NT stores.
// All selects exact on {0,1}: F(s) = f0 + s*(f1-f0).

typedef float v4f __attribute__((ext_vector_type(4)));

#define CHUNKS 16
#define CSTEPS 4   // rows per chunk; CHUNKS*CSTEPS = 64 = T
#define BCOLS  64  // v4f column groups per block (one wave-width)

__global__ __launch_bounds__(1024) void UnarySqrt_kernel(
    const v4f* __restrict__ in,      // [64, stride]
    const v4f* __restrict__ trace0,  // [stride]
    v4f* __restrict__ out,           // [64, stride]
    int stride)                       // N/4
{
    __shared__ v4f lds0[CHUNKS][BCOLS];  // F(0) per chunk x column
    __shared__ v4f lds1[CHUNKS][BCOLS];  // F(1)

    const int tid   = threadIdx.x;
    const int lane  = tid & 63;
    const int chunk = tid >> 6;                       // wave-uniform, 0..15
    const size_t g  = (size_t)blockIdx.x * BCOLS + lane;

    // ---- Phase 1: load this chunk's 4 rows + trace0, all independent ----
    v4f buf[CSTEPS];
    #pragma unroll
    for (int j = 0; j < CSTEPS; ++j) {
        buf[j] = in[(size_t)(chunk * CSTEPS + j) * (size_t)stride + g];
    }
    v4f s = trace0[g];
    // Force all loads issued before any use (batch materialization).
    asm volatile("" : "+v"(buf[0]), "+v"(buf[1]), "+v"(buf[2]), "+v"(buf[3]), "+v"(s));

    // ---- Phase 2: chunk transfer function from tr=0 and tr=1 ----
    v4f tr0 = {0.f, 0.f, 0.f, 0.f};
    v4f tr1 = {1.f, 1.f, 1.f, 1.f};
    #pragma unroll
    for (int j = 0; j < CSTEPS; ++j) {
        tr0 = buf[j] * (1.0f - tr0);
        tr1 = buf[j] * (1.0f - tr1);
    }
    lds0[chunk][lane] = tr0;
    lds1[chunk][lane] = tr1;
    __syncthreads();

    // ---- Phase 3: resolve incoming trace (wave-uniform trip count) ----
    for (int k = 0; k < chunk; ++k) {
        v4f a = lds0[k][lane];
        v4f b = lds1[k][lane];
        s = a + s * (b - a);  // s ? b : a, exact on {0,1}
    }

    // ---- Phase 4: recompute with real trace; 4 streaming stores ----
    v4f tr = s;
    #pragma unroll
    for (int j = 0; j < CSTEPS; ++j) {
        v4f p = buf[j] * (1.0f - tr);
        v4f o = tr + p;
        __builtin_nontemporal_store(
            o, &out[(size_t)(chunk * CSTEPS + j) * (size_t)stride + g]);
        tr = p;
    }
}

// Generic fallback (correct for any T, N%4==0).
__global__ __launch_bounds__(256) void UnarySqrt_generic(
    const v4f* __restrict__ in, const v4f* __restrict__ trace0,
    v4f* __restrict__ out, int stride, int T)
{
    int idx = blockIdx.x * blockDim.x + threadIdx.x;
    if (idx >= stride) return;
    v4f tr = trace0[idx];
    for (int t = 0; t < T; ++t) {
        v4f x = in[(size_t)t * stride + idx];
        v4f p = x * (1.0f - tr);
        out[(size_t)t * stride + idx] = tr + p;
        tr = p;
    }
}

extern "C" void kernel_launch(void* const* d_in, const int* in_sizes, int n_in,
                              void* d_out, int out_size, void* d_ws, size_t ws_size,
                              hipStream_t stream) {
    const float* bits   = (const float*)d_in[0];  // [T, N]
    const float* trace0 = (const float*)d_in[1];  // [N]

    int N = in_sizes[1];
    int T = in_sizes[0] / N;
    int stride = N / 4;

    if (T == 64 && (N % 256) == 0) {
        int grid = stride / BCOLS;  // 4096 blocks at N=2^20
        UnarySqrt_kernel<<<grid, 1024, 0, stream>>>(
            (const v4f*)bits, (const v4f*)trace0, (v4f*)d_out, stride);
    } else {
        int block = 256;
        int grid = (stride + block - 1) / block;
        UnarySqrt_generic<<<grid, block, 0, stream>>>(
            (const v4f*)bits, (const v4f*)trace0, (v4f*)d_out, stride, T);
    }
}